// Round 1
// baseline (184.568 us; speedup 1.0000x reference)
//
#include <hip/hip_runtime.h>
#include <stdint.h>

typedef unsigned short u16;
typedef __attribute__((ext_vector_type(8))) short bf16x8;
typedef __attribute__((ext_vector_type(4))) float f32x4;
typedef __attribute__((ext_vector_type(16))) float f32x16;
typedef __attribute__((ext_vector_type(4))) u16 us4;
typedef __attribute__((ext_vector_type(8))) u16 us8;

// ---------- helpers ----------
__device__ __forceinline__ u16 f2bf(float f) {
  union { float f; unsigned u; } v; v.f = f;
  unsigned r = v.u + 0x7fffu + ((v.u >> 16) & 1u);   // RNE
  return (u16)(r >> 16);
}

__device__ __forceinline__ float bf2f(u16 b) {
  union { float f; unsigned u; } v; v.u = ((unsigned)b) << 16;
  return v.f;
}

// pack two f32 -> bf16x2, RNE, single instruction (no builtin on gfx950)
__device__ __forceinline__ unsigned cvtpk(float a, float b) {
  unsigned r;
  asm("v_cvt_pk_bf16_f32 %0, %1, %2" : "=v"(r) : "v"(a), "v"(b));
  return r;
}

__device__ __forceinline__ float fast_exp2(float x) {
#if __has_builtin(__builtin_amdgcn_exp2f)
  return __builtin_amdgcn_exp2f(x);
#else
  return exp2f(x);
#endif
}

__device__ __forceinline__ void gld16(const void* g, void* l) {
  __builtin_amdgcn_global_load_lds(
      (const __attribute__((address_space(1))) void*)g,
      (__attribute__((address_space(3))) void*)l, 16, 0, 0);
}

// ---------- prep (merged): cvt x -> bf16; transpose-convert both W ----------
__global__ void prep_kernel(const float* __restrict__ x, u16* __restrict__ Xb,
                            const float* __restrict__ Wqkv, u16* __restrict__ Wqkt,
                            const float* __restrict__ Wproj, u16* __restrict__ Wpt) {
  __shared__ u16 tile[32][33];
  const int blk = blockIdx.x;
  if (blk < 4096) {
    const int i = blk * 256 + threadIdx.x;
    f32x4 v = ((const f32x4*)x)[i];
    us4 r;
#pragma unroll
    for (int j = 0; j < 4; ++j) r[j] = f2bf(v[j]);
    ((us4*)Xb)[i] = r;
    return;
  }
  const float* in;
  u16* out;
  int R, C, t;
  if (blk < 7168) { in = Wqkv; out = Wqkt; R = 1024; C = 3072; t = blk - 4096; }
  else            { in = Wproj; out = Wpt; R = 1024; C = 1024; t = blk - 7168; }
  const int gx = (C == 3072) ? (t % 96) : (t % 32);
  const int gy = (C == 3072) ? (t / 96) : (t / 32);
  const int tx = threadIdx.x & 31, ty = threadIdx.x >> 5;
  const int c0 = gx * 32, r0 = gy * 32;
#pragma unroll
  for (int j = 0; j < 4; ++j)
    tile[ty + j * 8][tx] = f2bf(in[(size_t)(r0 + ty + j * 8) * C + c0 + tx]);
  __syncthreads();
#pragma unroll
  for (int j = 0; j < 4; ++j)
    out[(size_t)(c0 + ty + j * 8) * R + r0 + tx] = tile[tx][ty + j * 8];
}

// ---------- QKV GEMM: [4096,1024]bf16 @ [3072,1024]bf16^T + bias ----------
// (r6 verbatim — proven) Q pre-scaled by 0.125*log2(e).
__global__ __launch_bounds__(256) void qkv_gemm_kernel(
    const u16* __restrict__ A, const u16* __restrict__ Bt, const float* __restrict__ bias,
    u16* __restrict__ Qb, u16* __restrict__ Kb, u16* __restrict__ Vtb) {
  __shared__ u16 sm[17408];
  u16* As = sm;
  u16* Bs = sm + 4096;
  const int tid = threadIdx.x;
  const int w = tid >> 6, l = tid & 63, quad = l >> 4, lanelo = l & 15;
  const int wr = w >> 1, wc = w & 1;
  const int flat = blockIdx.x + 32 * blockIdx.y;
  const int xcd = flat & 7, lid = flat >> 3;
  const long m0 = (long)((xcd >> 1) * 8 + (lid & 7)) * 128;
  const long n0 = (long)((xcd & 1) * 12 + (lid >> 3)) * 128;

  f32x4 acc[4][4];
#pragma unroll
  for (int i = 0; i < 4; ++i)
#pragma unroll
    for (int j = 0; j < 4; ++j) acc[i][j] = (f32x4){0.f, 0.f, 0.f, 0.f};

  const u16* ag = A + (m0 + w * 32 + (l >> 2)) * 1024 + (l & 3) * 8;
  const u16* bg = Bt + (n0 + w * 32 + (l >> 2)) * 1024 + (l & 3) * 8;
  u16* asl = As + w * 1024;
  u16* bsl = Bs + w * 1024;

  for (int kt = 0; kt < 32; ++kt) {
    const int ko = kt * 32;
    gld16(ag + ko, asl);
    gld16(ag + 16 * 1024 + ko, asl + 512);
    gld16(bg + ko, bsl);
    gld16(bg + 16 * 1024 + ko, bsl + 512);
    __syncthreads();
    bf16x8 af[4], bf[4];
#pragma unroll
    for (int mt = 0; mt < 4; ++mt)
      af[mt] = *(const bf16x8*)(As + (wr * 64 + mt * 16 + lanelo) * 32 + quad * 8);
#pragma unroll
    for (int nt = 0; nt < 4; ++nt)
      bf[nt] = *(const bf16x8*)(Bs + (wc * 64 + nt * 16 + lanelo) * 32 + quad * 8);
#pragma unroll
    for (int mt = 0; mt < 4; ++mt)
#pragma unroll
      for (int nt = 0; nt < 4; ++nt)
        acc[mt][nt] = __builtin_amdgcn_mfma_f32_16x16x32_bf16(af[mt], bf[nt], acc[mt][nt], 0, 0, 0);
    __syncthreads();
  }

  const int t = (int)(n0 >> 10);
  const float scl = (t == 0) ? 0.18033688011112042f : 1.0f;

  float bias_v[4];
#pragma unroll
  for (int nt = 0; nt < 4; ++nt) bias_v[nt] = bias[n0 + wc * 64 + nt * 16 + lanelo];

  u16* Ct = sm;  // [128][136]
#pragma unroll
  for (int mt = 0; mt < 4; ++mt)
#pragma unroll
    for (int nt = 0; nt < 4; ++nt)
#pragma unroll
      for (int r = 0; r < 4; ++r)
        Ct[(wr * 64 + mt * 16 + quad * 4 + r) * 136 + wc * 64 + nt * 16 + lanelo] =
            f2bf((acc[mt][nt][r] + bias_v[nt]) * scl);
  __syncthreads();

  const int b = (int)(m0 >> 11);
  const int s0 = (int)(m0 & 2047);
  const int h0 = (int)((n0 & 1023) >> 6);

  if (t < 2) {
    u16* dst = (t == 0) ? Qb : Kb;
#pragma unroll
    for (int p = 0; p < 8; ++p) {
      const int hh = p >> 2;
      const int sl = (p & 3) * 32 + (tid >> 3);
      const int c8 = tid & 7;
      us8 v = *(const us8*)(Ct + sl * 136 + hh * 64 + c8 * 8);
      const int pos = (c8 + sl) & 7;
      const size_t off = ((size_t)((b * 16 + h0 + hh) * 2048 + s0 + sl)) * 64 + pos * 8;
      *(us8*)(dst + off) = v;
    }
  } else {
#pragma unroll
    for (int p = 0; p < 8; ++p) {
      const int hh = p >> 2;
      const int dl = (p & 3) * 16 + (tid >> 4);
      const int c16 = tid & 15;
      us8 v;
#pragma unroll
      for (int j = 0; j < 8; ++j) v[j] = Ct[(c16 * 8 + j) * 136 + hh * 64 + dl];
      const int pos = (c16 + dl) & 15;
      const size_t off = ((size_t)((b * 16 + h0 + hh) * 64 + dl)) * 2048 + s0 + pos * 8;
      *(us8*)(Vtb + off) = v;
    }
  }
}

// ---------- flash attention: fused z-split, 512 threads ----------
// Wave-group z=tid>>8 handles keys [z*1024, z*1024+1024) with its own 32 KiB
// K/V slab. r9 change: the QK->PV softmax/repack path is rebuilt per T12:
//  - P f32->bf16 via v_cvt_pk_bf16_f32 (1 op/pair, was 3-op pkbf)
//  - cross-half exchange via v_permlane32_swap_b32 (VALU, 2 ops per s),
//    replacing 2x ds_bpermute (DS-pipe latency on the critical path) + 6
//    cndmask selects. Verified mapping: swap(W0,W2) -> {fd.x, fd.z},
//    swap(W1,W3) -> {fd.y, fd.w} for both lane halves.
//  - row-sum accumulated into 4 independent partials (f32 chain was 16-deep
//    per g; compiler can't reassociate).
// Everything else (swizzles, staging, barriers, epilogue) verbatim from r6.
__global__ __launch_bounds__(512, 4) void attn_kernel(
    const u16* __restrict__ Qb, const u16* __restrict__ Kb,
    const u16* __restrict__ Vtb, u16* __restrict__ Ob) {
  __shared__ u16 Ks[2][8192];   // per-z [key 128][dim 64]  8-chunk swizzled
  __shared__ u16 Vs[2][8192];   // per-z [dim 64][key 128] 16-chunk swizzled
  const int tid = threadIdx.x;
  const int w8 = tid >> 6;
  const int z = w8 >> 2, w = w8 & 3;   // z-group, wave within group
  const int l = tid & 63;
  const int m = l & 31, hi = l >> 5;
  const int fid = blockIdx.x;          // 0..511
  const int head = (fid & 7) + 8 * ((fid >> 3) & 3);   // 4 heads per XCD
  const int qt = fid >> 5;             // 0..15
  const u16* Qh = Qb + (size_t)head * 2048 * 64;
  const u16* Kh = Kb + (size_t)head * 2048 * 64;
  const u16* Vh = Vtb + (size_t)head * 64 * 2048;
  const int permaddr = (l ^ 32) << 2;

  // Q fragments (valid as B-operand: same per-lane layout)
  const int qrow = qt * 128 + w * 32 + m;
  bf16x8 qf[4];
#pragma unroll
  for (int ks = 0; ks < 4; ++ks) {
    const int pos = (ks * 2 + hi + qrow) & 7;
    qf[ks] = *(const bf16x8*)(Qh + (size_t)qrow * 64 + pos * 8);
  }

  f32x16 o0, o1;
#pragma unroll
  for (int i = 0; i < 16; ++i) { o0[i] = 0.f; o1[i] = 0.f; }
  float sp[4] = {0.f, 0.f, 0.f, 0.f};

  for (int kt = 0; kt < 8; ++kt) {
    const int kb = z * 8 + kt;
    const u16* kbase = Kh + (size_t)kb * 8192;
#pragma unroll
    for (int j = 0; j < 4; ++j) {
      const int i = w * 4 + j;
      gld16(kbase + i * 512 + l * 8, &Ks[z][i * 512]);
    }
#pragma unroll
    for (int j = 0; j < 4; ++j) {
      const int i = w * 4 + j;
      const int dd = i * 4 + (l >> 4);
      gld16(Vh + (size_t)dd * 2048 + kb * 128 + (l & 15) * 8, &Vs[z][i * 512]);
    }
    __syncthreads();

#pragma unroll
    for (int g = 0; g < 4; ++g) {
      f32x16 st;
#pragma unroll
      for (int i = 0; i < 16; ++i) st[i] = 0.f;
      const int key = g * 32 + m;
#pragma unroll
      for (int ks = 0; ks < 4; ++ks) {
        const int pos = (ks * 2 + hi + key) & 7;
        bf16x8 kf = *(const bf16x8*)(&Ks[z][key * 64 + pos * 8]);
        st = __builtin_amdgcn_mfma_f32_32x32x16_bf16(kf, qf[ks], st, 0, 0, 0);
      }

      float p[16];
#pragma unroll
      for (int r = 0; r < 16; ++r) p[r] = fast_exp2(st[r]);
      // 4 independent accumulation chains (depth 4 per g instead of 16)
#pragma unroll
      for (int r = 0; r < 16; ++r) sp[r & 3] += p[r];

      // pack P -> bf16 pairs: W[i] = {bf16(p[2i]) | bf16(p[2i+1]) << 16}
      unsigned W[8];
#pragma unroll
      for (int i = 0; i < 8; ++i) W[i] = cvtpk(p[2 * i], p[2 * i + 1]);

#pragma unroll
      for (int s = 0; s < 2; ++s) {
        // lane(hi) holds keys 16s+4hi+{0..3} in w0,w1 and 16s+8+4hi+{0..3}
        // in w2,w3; PV A-operand needs keys 16s+8hi+{0..7}.
        // permlane32_swap(w0,w2): w0' = [w0.lo|w2.lo] = fd.x (both halves),
        //                         w2' = [w0.hi|w2.hi] = fd.z (both halves).
        unsigned w0 = W[4 * s], w1 = W[4 * s + 1];
        unsigned w2 = W[4 * s + 2], w3 = W[4 * s + 3];
        asm("v_permlane32_swap_b32 %0, %1" : "+v"(w0), "+v"(w2));
        asm("v_permlane32_swap_b32 %0, %1" : "+v"(w1), "+v"(w3));
        int4 fd;
        fd.x = (int)w0;
        fd.y = (int)w1;
        fd.z = (int)w2;
        fd.w = (int)w3;
        union { int4 i; bf16x8 v; } pu; pu.i = fd;
        const int c = g * 4 + s * 2 + hi;   // key chunk for V B-operand
#pragma unroll
        for (int n = 0; n < 2; ++n) {
          const int d = n * 32 + m;
          const int pos = (c + d) & 15;
          bf16x8 vf = *(const bf16x8*)(&Vs[z][d * 128 + pos * 8]);
          if (n == 0) o0 = __builtin_amdgcn_mfma_f32_32x32x16_bf16(pu.v, vf, o0, 0, 0, 0);
          else        o1 = __builtin_amdgcn_mfma_f32_32x32x16_bf16(pu.v, vf, o1, 0, 0, 0);
        }
      }
    }
    __syncthreads();
  }

  const float sacc = (sp[0] + sp[1]) + (sp[2] + sp[3]);

  // per-z row-sum: own half + partner half (defined on all 64 lanes)
  union { float f; int i; } sv; sv.f = sacc;
  union { float f; int i; } pv; pv.i = __builtin_amdgcn_ds_bpermute(permaddr, sv.i);
  const float ltot = sacc + pv.f;

  // ---- in-block z combine (Ks/Vs are dead after the final loop barrier) ----
  float* Osl = (float*)Ks;   // 4 waves x 32 rows x 64 dims f32 = 32 KiB (exact)
  float* Lz1 = (float*)Vs;   // 4 waves x 32 rowsums

  if (z == 1) {
    if (hi == 0) Lz1[w * 32 + m] = ltot;
#pragma unroll
    for (int r = 0; r < 16; ++r) {
      const int qlocal = (r & 3) + 8 * (r >> 2) + 4 * hi;
      Osl[w * 2048 + qlocal * 64 + m] = o0[r];
      Osl[w * 2048 + qlocal * 64 + 32 + m] = o1[r];
    }
  }
  __syncthreads();
  if (z == 0) {
    const float lfull = ltot + Lz1[w * 32 + m];
    union { float f; int i; } li; li.f = 1.0f / lfull;   // linv for q-row = m
    const int b = head >> 4, h = head & 15;
#pragma unroll
    for (int r = 0; r < 16; ++r) {
      const int qlocal = (r & 3) + 8 * (r >> 2) + 4 * hi;
      union { float f; int i; } lg;
      lg.i = __builtin_amdgcn_ds_bpermute(qlocal << 2, li.i);  // linv for this row
      const float v0 = (o0[r] + Osl[w * 2048 + qlocal * 64 + m]) * lg.f;
      const float v1 = (o1[r] + Osl[w * 2048 + qlocal * 64 + 32 + m]) * lg.f;
      const size_t base =
          ((size_t)(b * 2048 + qt * 128 + w * 32 + qlocal)) * 1024 + h * 64;
      Ob[base + m] = f2bf(v0);
      Ob[base + 32 + m] = f2bf(v1);
    }
  }
}

// ---------- proj GEMM: 128x64 tiles, 512 blocks (2/CU), plain stores ----------
__global__ __launch_bounds__(256) void proj_gemm_kernel(
    const u16* __restrict__ A, const u16* __restrict__ Bt,
    const float* __restrict__ bias, float* __restrict__ out) {
  __shared__ u16 sm[6144];   // As 128x32 (4096) + Bs 64x32 (2048)
  u16* As = sm;
  u16* Bs = sm + 4096;
  const int tid = threadIdx.x;
  const int w = tid >> 6, l = tid & 63, quad = l >> 4, lanelo = l & 15;
  const int wr = w >> 1, wc = w & 1;
  const int flat = blockIdx.x + 32 * blockIdx.y;       // 0..511
  const int xcd = flat & 7, lid = flat >> 3;
  const long m0 = (long)(xcd * 4 + (lid & 3)) * 128;
  const long n0 = (long)(lid >> 2) * 64;

  f32x4 acc[4][2];
#pragma unroll
  for (int i = 0; i < 4; ++i)
#pragma unroll
    for (int j = 0; j < 2; ++j) acc[i][j] = (f32x4){0.f, 0.f, 0.f, 0.f};

  const u16* ag = A + (m0 + w * 32 + (l >> 2)) * 1024 + (l & 3) * 8;
  const u16* bg = Bt + (n0 + w * 16 + (l >> 2)) * 1024 + (l & 3) * 8;
  u16* asl = As + w * 1024;
  u16* bsl = Bs + w * 512;

  for (int kt = 0; kt < 32; ++kt) {
    const int ko = kt * 32;
    gld16(ag + ko, asl);
    gld16(ag + 16 * 1024 + ko, asl + 512);
    gld16(bg + ko, bsl);
    __syncthreads();
    bf16x8 af[4], bf[2];
#pragma unroll
    for (int mt = 0; mt < 4; ++mt)
      af[mt] = *(const bf16x8*)(As + (wr * 64 + mt * 16 + lanelo) * 32 + quad * 8);
#pragma unroll
    for (int nt = 0; nt < 2; ++nt)
      bf[nt] = *(const bf16x8*)(Bs + (wc * 32 + nt * 16 + lanelo) * 32 + quad * 8);
#pragma unroll
    for (int mt = 0; mt < 4; ++mt)
#pragma unroll
      for (int nt = 0; nt < 2; ++nt)
        acc[mt][nt] = __builtin_amdgcn_mfma_f32_16x16x32_bf16(af[mt], bf[nt], acc[mt][nt], 0, 0, 0);
    __syncthreads();
  }

  float bias_v[2];
#pragma unroll
  for (int nt = 0; nt < 2; ++nt)
    bias_v[nt] = bias[n0 + wc * 32 + nt * 16 + lanelo];

#pragma unroll
  for (int mt = 0; mt < 4; ++mt)
#pragma unroll
    for (int nt = 0; nt < 2; ++nt)
#pragma unroll
      for (int r = 0; r < 4; ++r) {
        const size_t mm = m0 + wr * 64 + mt * 16 + quad * 4 + r;
        const size_t nn = n0 + wc * 32 + nt * 16 + lanelo;
        out[mm * 1024 + nn] = acc[mt][nt][r] + bias_v[nt];
      }
}

// ---------- launch ----------
extern "C" void kernel_launch(void* const* d_in, const int* in_sizes, int n_in,
                              void* d_out, int out_size, void* d_ws, size_t ws_size,
                              hipStream_t stream) {
  const float* x = (const float*)d_in[0];
  const float* Wqkv = (const float*)d_in[1];
  const float* bqkv = (const float*)d_in[2];
  const float* Wproj = (const float*)d_in[3];
  const float* bproj = (const float*)d_in[4];
  float* out = (float*)d_out;
  char* ws = (char*)d_ws;

  // workspace layout (42 MB), lifetime-based aliasing:
  //  [ 0..8M)   Xb (dead after qkv) -> Ob (attn out / proj in)
  //  [ 8..16M)  Wqkt ; [16..24M) Qb ; [24..32M) Kb ; [32..40M) Vtb ; [40..42M) Wpt
  u16* Xb   = (u16*)(ws);
  u16* Ob   = (u16*)(ws);
  u16* Wqkt = (u16*)(ws + 8388608);
  u16* Qb   = (u16*)(ws + 16777216);
  u16* Kb   = (u16*)(ws + 25165824);
  u16* Vtb  = (u16*)(ws + 33554432);
  u16* Wpt  = (u16*)(ws + 41943040);

  prep_kernel<<<8192, 256, 0, stream>>>(x, Xb, Wqkv, Wqkt, Wproj, Wpt);
  qkv_gemm_kernel<<<dim3(32, 24), 256, 0, stream>>>(Xb, Wqkt, bqkv, Qb, Kb, Vtb);
  attn_kernel<<<512, 512, 0, stream>>>(Qb, Kb, Vtb, Ob);
  proj_gemm_kernel<<<dim3(32, 16), 256, 0, stream>>>(Ob, Wpt, bproj, out);
}

// Round 2
// 183.997 us; speedup vs baseline: 1.0031x; 1.0031x over previous
//
#include <hip/hip_runtime.h>
#include <stdint.h>

typedef unsigned short u16;
typedef __attribute__((ext_vector_type(8))) short bf16x8;
typedef __attribute__((ext_vector_type(4))) float f32x4;
typedef __attribute__((ext_vector_type(16))) float f32x16;
typedef __attribute__((ext_vector_type(4))) u16 us4;
typedef __attribute__((ext_vector_type(8))) u16 us8;

// ---------- helpers ----------
__device__ __forceinline__ u16 f2bf(float f) {
  union { float f; unsigned u; } v; v.f = f;
  unsigned r = v.u + 0x7fffu + ((v.u >> 16) & 1u);   // RNE
  return (u16)(r >> 16);
}

__device__ __forceinline__ float bf2f(u16 b) {
  union { float f; unsigned u; } v; v.u = ((unsigned)b) << 16;
  return v.f;
}

// pack two f32 -> bf16x2, RNE, single instruction (no builtin on gfx950)
__device__ __forceinline__ unsigned cvtpk(float a, float b) {
  unsigned r;
  asm("v_cvt_pk_bf16_f32 %0, %1, %2" : "=v"(r) : "v"(a), "v"(b));
  return r;
}

__device__ __forceinline__ float fast_exp2(float x) {
#if __has_builtin(__builtin_amdgcn_exp2f)
  return __builtin_amdgcn_exp2f(x);
#else
  return exp2f(x);
#endif
}

__device__ __forceinline__ void gld16(const void* g, void* l) {
  __builtin_amdgcn_global_load_lds(
      (const __attribute__((address_space(1))) void*)g,
      (__attribute__((address_space(3))) void*)l, 16, 0, 0);
}

// ---------- prep (merged): cvt x -> bf16; transpose-convert both W ----------
__global__ void prep_kernel(const float* __restrict__ x, u16* __restrict__ Xb,
                            const float* __restrict__ Wqkv, u16* __restrict__ Wqkt,
                            const float* __restrict__ Wproj, u16* __restrict__ Wpt) {
  __shared__ u16 tile[32][33];
  const int blk = blockIdx.x;
  if (blk < 4096) {
    const int i = blk * 256 + threadIdx.x;
    f32x4 v = ((const f32x4*)x)[i];
    us4 r;
#pragma unroll
    for (int j = 0; j < 4; ++j) r[j] = f2bf(v[j]);
    ((us4*)Xb)[i] = r;
    return;
  }
  const float* in;
  u16* out;
  int R, C, t;
  if (blk < 7168) { in = Wqkv; out = Wqkt; R = 1024; C = 3072; t = blk - 4096; }
  else            { in = Wproj; out = Wpt; R = 1024; C = 1024; t = blk - 7168; }
  const int gx = (C == 3072) ? (t % 96) : (t % 32);
  const int gy = (C == 3072) ? (t / 96) : (t / 32);
  const int tx = threadIdx.x & 31, ty = threadIdx.x >> 5;
  const int c0 = gx * 32, r0 = gy * 32;
#pragma unroll
  for (int j = 0; j < 4; ++j)
    tile[ty + j * 8][tx] = f2bf(in[(size_t)(r0 + ty + j * 8) * C + c0 + tx]);
  __syncthreads();
#pragma unroll
  for (int j = 0; j < 4; ++j)
    out[(size_t)(c0 + ty + j * 8) * R + r0 + tx] = tile[tx][ty + j * 8];
}

// ---------- QKV GEMM: [4096,1024]bf16 @ [3072,1024]bf16^T + bias ----------
// (r6 verbatim — proven) Q pre-scaled by 0.125*log2(e).
__global__ __launch_bounds__(256) void qkv_gemm_kernel(
    const u16* __restrict__ A, const u16* __restrict__ Bt, const float* __restrict__ bias,
    u16* __restrict__ Qb, u16* __restrict__ Kb, u16* __restrict__ Vtb) {
  __shared__ u16 sm[17408];
  u16* As = sm;
  u16* Bs = sm + 4096;
  const int tid = threadIdx.x;
  const int w = tid >> 6, l = tid & 63, quad = l >> 4, lanelo = l & 15;
  const int wr = w >> 1, wc = w & 1;
  const int flat = blockIdx.x + 32 * blockIdx.y;
  const int xcd = flat & 7, lid = flat >> 3;
  const long m0 = (long)((xcd >> 1) * 8 + (lid & 7)) * 128;
  const long n0 = (long)((xcd & 1) * 12 + (lid >> 3)) * 128;

  f32x4 acc[4][4];
#pragma unroll
  for (int i = 0; i < 4; ++i)
#pragma unroll
    for (int j = 0; j < 4; ++j) acc[i][j] = (f32x4){0.f, 0.f, 0.f, 0.f};

  const u16* ag = A + (m0 + w * 32 + (l >> 2)) * 1024 + (l & 3) * 8;
  const u16* bg = Bt + (n0 + w * 32 + (l >> 2)) * 1024 + (l & 3) * 8;
  u16* asl = As + w * 1024;
  u16* bsl = Bs + w * 1024;

  for (int kt = 0; kt < 32; ++kt) {
    const int ko = kt * 32;
    gld16(ag + ko, asl);
    gld16(ag + 16 * 1024 + ko, asl + 512);
    gld16(bg + ko, bsl);
    gld16(bg + 16 * 1024 + ko, bsl + 512);
    __syncthreads();
    bf16x8 af[4], bf[4];
#pragma unroll
    for (int mt = 0; mt < 4; ++mt)
      af[mt] = *(const bf16x8*)(As + (wr * 64 + mt * 16 + lanelo) * 32 + quad * 8);
#pragma unroll
    for (int nt = 0; nt < 4; ++nt)
      bf[nt] = *(const bf16x8*)(Bs + (wc * 64 + nt * 16 + lanelo) * 32 + quad * 8);
#pragma unroll
    for (int mt = 0; mt < 4; ++mt)
#pragma unroll
      for (int nt = 0; nt < 4; ++nt)
        acc[mt][nt] = __builtin_amdgcn_mfma_f32_16x16x32_bf16(af[mt], bf[nt], acc[mt][nt], 0, 0, 0);
    __syncthreads();
  }

  const int t = (int)(n0 >> 10);
  const float scl = (t == 0) ? 0.18033688011112042f : 1.0f;

  float bias_v[4];
#pragma unroll
  for (int nt = 0; nt < 4; ++nt) bias_v[nt] = bias[n0 + wc * 64 + nt * 16 + lanelo];

  u16* Ct = sm;  // [128][136]
#pragma unroll
  for (int mt = 0; mt < 4; ++mt)
#pragma unroll
    for (int nt = 0; nt < 4; ++nt)
#pragma unroll
      for (int r = 0; r < 4; ++r)
        Ct[(wr * 64 + mt * 16 + quad * 4 + r) * 136 + wc * 64 + nt * 16 + lanelo] =
            f2bf((acc[mt][nt][r] + bias_v[nt]) * scl);
  __syncthreads();

  const int b = (int)(m0 >> 11);
  const int s0 = (int)(m0 & 2047);
  const int h0 = (int)((n0 & 1023) >> 6);

  if (t < 2) {
    u16* dst = (t == 0) ? Qb : Kb;
#pragma unroll
    for (int p = 0; p < 8; ++p) {
      const int hh = p >> 2;
      const int sl = (p & 3) * 32 + (tid >> 3);
      const int c8 = tid & 7;
      us8 v = *(const us8*)(Ct + sl * 136 + hh * 64 + c8 * 8);
      const int pos = (c8 + sl) & 7;
      const size_t off = ((size_t)((b * 16 + h0 + hh) * 2048 + s0 + sl)) * 64 + pos * 8;
      *(us8*)(dst + off) = v;
    }
  } else {
#pragma unroll
    for (int p = 0; p < 8; ++p) {
      const int hh = p >> 2;
      const int dl = (p & 3) * 16 + (tid >> 4);
      const int c16 = tid & 15;
      us8 v;
#pragma unroll
      for (int j = 0; j < 8; ++j) v[j] = Ct[(c16 * 8 + j) * 136 + hh * 64 + dl];
      const int pos = (c16 + dl) & 15;
      const size_t off = ((size_t)((b * 16 + h0 + hh) * 64 + dl)) * 2048 + s0 + pos * 8;
      *(us8*)(Vtb + off) = v;
    }
  }
}

// ---------- flash attention: fused z-split, 512 threads ----------
// r10 change (T3-minimal double-buffer): K/V tile halved to 64 keys (16 kt),
// double-buffered in the SAME 64 KiB LDS (2z x 2buf x 8KB K + 8KB V).
// Per kt: raw s_barrier (prev-buf readers done) -> issue 4 gld16 for kt+1
// -> s_waitcnt vmcnt(4) (kt's loads done, kt+1's stay IN FLIGHT across the
// barrier) -> raw s_barrier -> compute. __syncthreads() would drain vmcnt(0)
// and kill the overlap, hence raw barriers + manual counted waits (guide
// T3/T4; m201-proven pattern). V source swizzle (mod-16 over 128-key panels)
// re-derived per-lane for 64-key tiles: gld16's global source is per-lane,
// LDS dest stays linear; LDS V layout [dim64][chunk8] with pos=(c+d)&7 so
// read-back conflicts match the old 4-way level. Softmax path (T12 cvtpk +
// permlane32_swap) and epilogue unchanged; one extra post-loop barrier since
// the loop no longer ends in one.
__global__ __launch_bounds__(512, 4) void attn_kernel(
    const u16* __restrict__ Qb, const u16* __restrict__ Kb,
    const u16* __restrict__ Vtb, u16* __restrict__ Ob) {
  __shared__ u16 Ks[2][2][4096];   // [z][buf][key 64][dim 64] 8-chunk swizzled
  __shared__ u16 Vs[2][2][4096];   // [z][buf][dim 64][key 64] 8-chunk swizzled
  const int tid = threadIdx.x;
  const int w8 = tid >> 6;
  const int z = w8 >> 2, w = w8 & 3;   // z-group, wave within group
  const int l = tid & 63;
  const int m = l & 31, hi = l >> 5;
  const int fid = blockIdx.x;          // 0..511
  const int head = (fid & 7) + 8 * ((fid >> 3) & 3);   // 4 heads per XCD
  const int qt = fid >> 5;             // 0..15
  const u16* Qh = Qb + (size_t)head * 2048 * 64;
  const u16* Kh = Kb + (size_t)head * 2048 * 64;
  const u16* Vh = Vtb + (size_t)head * 64 * 2048;
  const int permaddr = (l ^ 32) << 2;

  // Q fragments (valid as B-operand: same per-lane layout)
  const int qrow = qt * 128 + w * 32 + m;
  bf16x8 qf[4];
#pragma unroll
  for (int ks = 0; ks < 4; ++ks) {
    const int pos = (ks * 2 + hi + qrow) & 7;
    qf[ks] = *(const bf16x8*)(Qh + (size_t)qrow * 64 + pos * 8);
  }

  f32x16 o0, o1;
#pragma unroll
  for (int i = 0; i < 16; ++i) { o0[i] = 0.f; o1[i] = 0.f; }
  float sp[4] = {0.f, 0.f, 0.f, 0.f};

  // stage 64-key block kb (absolute, 0..31) into buf
  auto stage = [&](int kb, int buf) {
    const u16* kbase = Kh + (size_t)kb * 4096;
#pragma unroll
    for (int j = 0; j < 2; ++j) {
      const int i = w * 2 + j;                     // 0..7: 8 key-rows each
      gld16(kbase + i * 512 + l * 8, &Ks[z][buf][i * 512]);
    }
    const int panel = kb >> 1, half = kb & 1;
#pragma unroll
    for (int j = 0; j < 2; ++j) {
      const int i = w * 2 + j;                     // 0..7: 8 dim-rows each
      const int dd = i * 8 + (l >> 3);
      const int p = l & 7;                          // LDS slot within row
      const int q = (p - dd) & 7;                   // local key-chunk at slot p
      const int pos16 = (half * 8 + q + dd) & 15;   // stored position in Vtb
      gld16(Vh + (size_t)dd * 2048 + panel * 128 + pos16 * 8,
            &Vs[z][buf][i * 512]);
    }
  };

  int cur = 0;
  stage(z * 16, 0);

  for (int kt = 0; kt < 16; ++kt) {
    __builtin_amdgcn_s_barrier();      // buf[cur^1] readers (kt-1) done
    if (kt < 15) {
      stage(z * 16 + kt + 1, cur ^ 1);
      asm volatile("s_waitcnt vmcnt(4)" ::: "memory");  // kt's 4 landed
    } else {
      asm volatile("s_waitcnt vmcnt(0)" ::: "memory");
    }
    __builtin_amdgcn_s_barrier();      // buf[cur] visible block-wide

#pragma unroll
    for (int g = 0; g < 2; ++g) {
      f32x16 st;
#pragma unroll
      for (int i = 0; i < 16; ++i) st[i] = 0.f;
      const int key = g * 32 + m;
#pragma unroll
      for (int ks = 0; ks < 4; ++ks) {
        const int pos = (ks * 2 + hi + key) & 7;
        bf16x8 kf = *(const bf16x8*)(&Ks[z][cur][key * 64 + pos * 8]);
        st = __builtin_amdgcn_mfma_f32_32x32x16_bf16(kf, qf[ks], st, 0, 0, 0);
      }

      float p[16];
#pragma unroll
      for (int r = 0; r < 16; ++r) p[r] = fast_exp2(st[r]);
#pragma unroll
      for (int r = 0; r < 16; ++r) sp[r & 3] += p[r];

      unsigned W[8];
#pragma unroll
      for (int i = 0; i < 8; ++i) W[i] = cvtpk(p[2 * i], p[2 * i + 1]);

#pragma unroll
      for (int s = 0; s < 2; ++s) {
        unsigned w0 = W[4 * s], w1 = W[4 * s + 1];
        unsigned w2 = W[4 * s + 2], w3 = W[4 * s + 3];
        asm("v_permlane32_swap_b32 %0, %1" : "+v"(w0), "+v"(w2));
        asm("v_permlane32_swap_b32 %0, %1" : "+v"(w1), "+v"(w3));
        int4 fd;
        fd.x = (int)w0;
        fd.y = (int)w1;
        fd.z = (int)w2;
        fd.w = (int)w3;
        union { int4 i; bf16x8 v; } pu; pu.i = fd;
        const int c = g * 4 + s * 2 + hi;   // local key chunk 0..7
#pragma unroll
        for (int n = 0; n < 2; ++n) {
          const int d = n * 32 + m;
          const int pos = (c + d) & 7;
          bf16x8 vf = *(const bf16x8*)(&Vs[z][cur][d * 64 + pos * 8]);
          if (n == 0) o0 = __builtin_amdgcn_mfma_f32_32x32x16_bf16(pu.v, vf, o0, 0, 0, 0);
          else        o1 = __builtin_amdgcn_mfma_f32_32x32x16_bf16(pu.v, vf, o1, 0, 0, 0);
        }
      }
    }
    cur ^= 1;
  }
  __syncthreads();   // all compute done before Ks/Vs are reused below

  const float sacc = (sp[0] + sp[1]) + (sp[2] + sp[3]);

  // per-z row-sum: own half + partner half (defined on all 64 lanes)
  union { float f; int i; } sv; sv.f = sacc;
  union { float f; int i; } pv; pv.i = __builtin_amdgcn_ds_bpermute(permaddr, sv.i);
  const float ltot = sacc + pv.f;

  // ---- in-block z combine (Ks/Vs are dead after the post-loop barrier) ----
  float* Osl = (float*)Ks;   // 4 waves x 32 rows x 64 dims f32 = 32 KiB (exact)
  float* Lz1 = (float*)Vs;   // 4 waves x 32 rowsums

  if (z == 1) {
    if (hi == 0) Lz1[w * 32 + m] = ltot;
#pragma unroll
    for (int r = 0; r < 16; ++r) {
      const int qlocal = (r & 3) + 8 * (r >> 2) + 4 * hi;
      Osl[w * 2048 + qlocal * 64 + m] = o0[r];
      Osl[w * 2048 + qlocal * 64 + 32 + m] = o1[r];
    }
  }
  __syncthreads();
  if (z == 0) {
    const float lfull = ltot + Lz1[w * 32 + m];
    union { float f; int i; } li; li.f = 1.0f / lfull;   // linv for q-row = m
    const int b = head >> 4, h = head & 15;
#pragma unroll
    for (int r = 0; r < 16; ++r) {
      const int qlocal = (r & 3) + 8 * (r >> 2) + 4 * hi;
      union { float f; int i; } lg;
      lg.i = __builtin_amdgcn_ds_bpermute(qlocal << 2, li.i);  // linv for this row
      const float v0 = (o0[r] + Osl[w * 2048 + qlocal * 64 + m]) * lg.f;
      const float v1 = (o1[r] + Osl[w * 2048 + qlocal * 64 + 32 + m]) * lg.f;
      const size_t base =
          ((size_t)(b * 2048 + qt * 128 + w * 32 + qlocal)) * 1024 + h * 64;
      Ob[base + m] = f2bf(v0);
      Ob[base + 32 + m] = f2bf(v1);
    }
  }
}

// ---------- proj GEMM: 128x64 tiles, 512 blocks (2/CU), plain stores ----------
__global__ __launch_bounds__(256) void proj_gemm_kernel(
    const u16* __restrict__ A, const u16* __restrict__ Bt,
    const float* __restrict__ bias, float* __restrict__ out) {
  __shared__ u16 sm[6144];   // As 128x32 (4096) + Bs 64x32 (2048)
  u16* As = sm;
  u16* Bs = sm + 4096;
  const int tid = threadIdx.x;
  const int w = tid >> 6, l = tid & 63, quad = l >> 4, lanelo = l & 15;
  const int wr = w >> 1, wc = w & 1;
  const int flat = blockIdx.x + 32 * blockIdx.y;       // 0..511
  const int xcd = flat & 7, lid = flat >> 3;
  const long m0 = (long)(xcd * 4 + (lid & 3)) * 128;
  const long n0 = (long)(lid >> 2) * 64;

  f32x4 acc[4][2];
#pragma unroll
  for (int i = 0; i < 4; ++i)
#pragma unroll
    for (int j = 0; j < 2; ++j) acc[i][j] = (f32x4){0.f, 0.f, 0.f, 0.f};

  const u16* ag = A + (m0 + w * 32 + (l >> 2)) * 1024 + (l & 3) * 8;
  const u16* bg = Bt + (n0 + w * 16 + (l >> 2)) * 1024 + (l & 3) * 8;
  u16* asl = As + w * 1024;
  u16* bsl = Bs + w * 512;

  for (int kt = 0; kt < 32; ++kt) {
    const int ko = kt * 32;
    gld16(ag + ko, asl);
    gld16(ag + 16 * 1024 + ko, asl + 512);
    gld16(bg + ko, bsl);
    __syncthreads();
    bf16x8 af[4], bf[2];
#pragma unroll
    for (int mt = 0; mt < 4; ++mt)
      af[mt] = *(const bf16x8*)(As + (wr * 64 + mt * 16 + lanelo) * 32 + quad * 8);
#pragma unroll
    for (int nt = 0; nt < 2; ++nt)
      bf[nt] = *(const bf16x8*)(Bs + (wc * 32 + nt * 16 + lanelo) * 32 + quad * 8);
#pragma unroll
    for (int mt = 0; mt < 4; ++mt)
#pragma unroll
      for (int nt = 0; nt < 2; ++nt)
        acc[mt][nt] = __builtin_amdgcn_mfma_f32_16x16x32_bf16(af[mt], bf[nt], acc[mt][nt], 0, 0, 0);
    __syncthreads();
  }

  float bias_v[2];
#pragma unroll
  for (int nt = 0; nt < 2; ++nt)
    bias_v[nt] = bias[n0 + wc * 32 + nt * 16 + lanelo];

#pragma unroll
  for (int mt = 0; mt < 4; ++mt)
#pragma unroll
    for (int nt = 0; nt < 2; ++nt)
#pragma unroll
      for (int r = 0; r < 4; ++r) {
        const size_t mm = m0 + wr * 64 + mt * 16 + quad * 4 + r;
        const size_t nn = n0 + wc * 32 + nt * 16 + lanelo;
        out[mm * 1024 + nn] = acc[mt][nt][r] + bias_v[nt];
      }
}

// ---------- launch ----------
extern "C" void kernel_launch(void* const* d_in, const int* in_sizes, int n_in,
                              void* d_out, int out_size, void* d_ws, size_t ws_size,
                              hipStream_t stream) {
  const float* x = (const float*)d_in[0];
  const float* Wqkv = (const float*)d_in[1];
  const float* bqkv = (const float*)d_in[2];
  const float* Wproj = (const float*)d_in[3];
  const float* bproj = (const float*)d_in[4];
  float* out = (float*)d_out;
  char* ws = (char*)d_ws;

  // workspace layout (42 MB), lifetime-based aliasing:
  //  [ 0..8M)   Xb (dead after qkv) -> Ob (attn out / proj in)
  //  [ 8..16M)  Wqkt ; [16..24M) Qb ; [24..32M) Kb ; [32..40M) Vtb ; [40..42M) Wpt
  u16* Xb   = (u16*)(ws);
  u16* Ob   = (u16*)(ws);
  u16* Wqkt = (u16*)(ws + 8388608);
  u16* Qb   = (u16*)(ws + 16777216);
  u16* Kb   = (u16*)(ws + 25165824);
  u16* Vtb  = (u16*)(ws + 33554432);
  u16* Wpt  = (u16*)(ws + 41943040);

  prep_kernel<<<8192, 256, 0, stream>>>(x, Xb, Wqkv, Wqkt, Wproj, Wpt);
  qkv_gemm_kernel<<<dim3(32, 24), 256, 0, stream>>>(Xb, Wqkt, bqkv, Qb, Kb, Vtb);
  attn_kernel<<<512, 512, 0, stream>>>(Qb, Kb, Vtb, Ob);
  proj_gemm_kernel<<<dim3(32, 16), 256, 0, stream>>>(Ob, Wpt, bproj, out);
}

// Round 3
// 183.011 us; speedup vs baseline: 1.0085x; 1.0054x over previous
//
#include <hip/hip_runtime.h>
#include <stdint.h>

typedef unsigned short u16;
typedef __attribute__((ext_vector_type(8))) short bf16x8;
typedef __attribute__((ext_vector_type(4))) float f32x4;
typedef __attribute__((ext_vector_type(16))) float f32x16;
typedef __attribute__((ext_vector_type(4))) u16 us4;
typedef __attribute__((ext_vector_type(8))) u16 us8;

// ---------- helpers ----------
__device__ __forceinline__ u16 f2bf(float f) {
  union { float f; unsigned u; } v; v.f = f;
  unsigned r = v.u + 0x7fffu + ((v.u >> 16) & 1u);   // RNE
  return (u16)(r >> 16);
}

// pack two f32 -> bf16x2, RNE, single instruction (no builtin on gfx950)
__device__ __forceinline__ unsigned cvtpk(float a, float b) {
  unsigned r;
  asm("v_cvt_pk_bf16_f32 %0, %1, %2" : "=v"(r) : "v"(a), "v"(b));
  return r;
}

__device__ __forceinline__ float fast_exp2(float x) {
#if __has_builtin(__builtin_amdgcn_exp2f)
  return __builtin_amdgcn_exp2f(x);
#else
  return exp2f(x);
#endif
}

__device__ __forceinline__ void gld16(const void* g, void* l) {
  __builtin_amdgcn_global_load_lds(
      (const __attribute__((address_space(1))) void*)g,
      (__attribute__((address_space(3))) void*)l, 16, 0, 0);
}

// ---------- prep (merged): cvt x -> bf16; transpose-convert both W ----------
// r11: W-transpose tiles 64(r) x 32(c); writes are us8 (16 B/lane, 128 B per
// output-row segment) instead of scalar u16 (was 64 B/wave-row transactions).
__global__ void prep_kernel(const float* __restrict__ x, u16* __restrict__ Xb,
                            const float* __restrict__ Wqkv, u16* __restrict__ Wqkt,
                            const float* __restrict__ Wproj, u16* __restrict__ Wpt) {
  __shared__ u16 tile[64][33];
  const int blk = blockIdx.x;
  if (blk < 4096) {
    const int i = blk * 256 + threadIdx.x;
    f32x4 v = ((const f32x4*)x)[i];
    us4 r;
#pragma unroll
    for (int j = 0; j < 4; ++j) r[j] = f2bf(v[j]);
    ((us4*)Xb)[i] = r;
    return;
  }
  const float* in;
  u16* out;
  int C, t;
  if (blk < 5632) { in = Wqkv; out = Wqkt; C = 3072; t = blk - 4096; }   // 96x16 tiles
  else            { in = Wproj; out = Wpt; C = 1024; t = blk - 5632; }   // 32x16 tiles
  const int R = 1024;
  const int gx = (C == 3072) ? (t % 96) : (t % 32);
  const int gy = (C == 3072) ? (t / 96) : (t / 32);
  const int tx = threadIdx.x & 31, ty = threadIdx.x >> 5;   // c, r-base
  const int c0 = gx * 32, r0 = gy * 64;
#pragma unroll
  for (int j = 0; j < 8; ++j)
    tile[ty + j * 8][tx] = f2bf(in[(size_t)(r0 + ty + j * 8) * C + c0 + tx]);
  __syncthreads();
  // thread -> output row (c0+oc), 8 consecutive r elements starting at ob
  const int oc = threadIdx.x >> 3, ob = (threadIdx.x & 7) * 8;
  us8 o;
#pragma unroll
  for (int k = 0; k < 8; ++k) o[k] = tile[ob + k][oc];
  *(us8*)(&out[(size_t)(c0 + oc) * R + r0 + ob]) = o;
}

// ---------- QKV GEMM: [4096,1024]bf16 @ [3072,1024]bf16^T + bias ----------
// (r6 verbatim — proven) Q pre-scaled by 0.125*log2(e).
__global__ __launch_bounds__(256) void qkv_gemm_kernel(
    const u16* __restrict__ A, const u16* __restrict__ Bt, const float* __restrict__ bias,
    u16* __restrict__ Qb, u16* __restrict__ Kb, u16* __restrict__ Vtb) {
  __shared__ u16 sm[17408];
  u16* As = sm;
  u16* Bs = sm + 4096;
  const int tid = threadIdx.x;
  const int w = tid >> 6, l = tid & 63, quad = l >> 4, lanelo = l & 15;
  const int wr = w >> 1, wc = w & 1;
  const int flat = blockIdx.x + 32 * blockIdx.y;
  const int xcd = flat & 7, lid = flat >> 3;
  const long m0 = (long)((xcd >> 1) * 8 + (lid & 7)) * 128;
  const long n0 = (long)((xcd & 1) * 12 + (lid >> 3)) * 128;

  f32x4 acc[4][4];
#pragma unroll
  for (int i = 0; i < 4; ++i)
#pragma unroll
    for (int j = 0; j < 4; ++j) acc[i][j] = (f32x4){0.f, 0.f, 0.f, 0.f};

  const u16* ag = A + (m0 + w * 32 + (l >> 2)) * 1024 + (l & 3) * 8;
  const u16* bg = Bt + (n0 + w * 32 + (l >> 2)) * 1024 + (l & 3) * 8;
  u16* asl = As + w * 1024;
  u16* bsl = Bs + w * 1024;

  for (int kt = 0; kt < 32; ++kt) {
    const int ko = kt * 32;
    gld16(ag + ko, asl);
    gld16(ag + 16 * 1024 + ko, asl + 512);
    gld16(bg + ko, bsl);
    gld16(bg + 16 * 1024 + ko, bsl + 512);
    __syncthreads();
    bf16x8 af[4], bf[4];
#pragma unroll
    for (int mt = 0; mt < 4; ++mt)
      af[mt] = *(const bf16x8*)(As + (wr * 64 + mt * 16 + lanelo) * 32 + quad * 8);
#pragma unroll
    for (int nt = 0; nt < 4; ++nt)
      bf[nt] = *(const bf16x8*)(Bs + (wc * 64 + nt * 16 + lanelo) * 32 + quad * 8);
#pragma unroll
    for (int mt = 0; mt < 4; ++mt)
#pragma unroll
      for (int nt = 0; nt < 4; ++nt)
        acc[mt][nt] = __builtin_amdgcn_mfma_f32_16x16x32_bf16(af[mt], bf[nt], acc[mt][nt], 0, 0, 0);
    __syncthreads();
  }

  const int t = (int)(n0 >> 10);
  const float scl = (t == 0) ? 0.18033688011112042f : 1.0f;

  float bias_v[4];
#pragma unroll
  for (int nt = 0; nt < 4; ++nt) bias_v[nt] = bias[n0 + wc * 64 + nt * 16 + lanelo];

  u16* Ct = sm;  // [128][136]
#pragma unroll
  for (int mt = 0; mt < 4; ++mt)
#pragma unroll
    for (int nt = 0; nt < 4; ++nt)
#pragma unroll
      for (int r = 0; r < 4; ++r)
        Ct[(wr * 64 + mt * 16 + quad * 4 + r) * 136 + wc * 64 + nt * 16 + lanelo] =
            f2bf((acc[mt][nt][r] + bias_v[nt]) * scl);
  __syncthreads();

  const int b = (int)(m0 >> 11);
  const int s0 = (int)(m0 & 2047);
  const int h0 = (int)((n0 & 1023) >> 6);

  if (t < 2) {
    u16* dst = (t == 0) ? Qb : Kb;
#pragma unroll
    for (int p = 0; p < 8; ++p) {
      const int hh = p >> 2;
      const int sl = (p & 3) * 32 + (tid >> 3);
      const int c8 = tid & 7;
      us8 v = *(const us8*)(Ct + sl * 136 + hh * 64 + c8 * 8);
      const int pos = (c8 + sl) & 7;
      const size_t off = ((size_t)((b * 16 + h0 + hh) * 2048 + s0 + sl)) * 64 + pos * 8;
      *(us8*)(dst + off) = v;
    }
  } else {
#pragma unroll
    for (int p = 0; p < 8; ++p) {
      const int hh = p >> 2;
      const int dl = (p & 3) * 16 + (tid >> 4);
      const int c16 = tid & 15;
      us8 v;
#pragma unroll
      for (int j = 0; j < 8; ++j) v[j] = Ct[(c16 * 8 + j) * 136 + hh * 64 + dl];
      const int pos = (c16 + dl) & 15;
      const size_t off = ((size_t)((b * 16 + h0 + hh) * 64 + dl)) * 2048 + s0 + pos * 8;
      *(us8*)(Vtb + off) = v;
    }
  }
}

// ---------- flash attention: fused z-split, 512 threads ----------
// r11 changes (VALU-cut bundle; structure/barriers/vmcnt identical to r10):
//  1. Row-sum via ones-MFMA: sl = mfma(P, ones, sl) per (g,s) replaces the
//     32 serial sp-adds per g AND the epilogue cross-lane bpermute sums.
//     sl[r] has exactly o0's row layout (row = qlocal), so normalization is
//     per-row local. Normalizing by sum of the bf16 P actually fed to PV.
//  2. Stage addresses (incl. both V parity swizzles) hoisted to per-lane
//     constants; per kt = select + add (round-2 VALUBusy +10 was this).
//  3. T5 s_setprio(1/0) around QK and PV MFMA clusters.
__global__ __launch_bounds__(512, 4) void attn_kernel(
    const u16* __restrict__ Qb, const u16* __restrict__ Kb,
    const u16* __restrict__ Vtb, u16* __restrict__ Ob) {
  __shared__ u16 Ks[2][2][4096];   // [z][buf][key 64][dim 64] 8-chunk swizzled
  __shared__ u16 Vs[2][2][4096];   // [z][buf][dim 64][key 64] 8-chunk swizzled
  const int tid = threadIdx.x;
  const int w8 = tid >> 6;
  const int z = w8 >> 2, w = w8 & 3;   // z-group, wave within group
  const int l = tid & 63;
  const int m = l & 31, hi = l >> 5;
  const int fid = blockIdx.x;          // 0..511
  const int head = (fid & 7) + 8 * ((fid >> 3) & 3);   // 4 heads per XCD
  const int qt = fid >> 5;             // 0..15
  const u16* Qh = Qb + (size_t)head * 2048 * 64;
  const u16* Kh = Kb + (size_t)head * 2048 * 64;
  const u16* Vh = Vtb + (size_t)head * 64 * 2048;

  // Q fragments (valid as B-operand: same per-lane layout)
  const int qrow = qt * 128 + w * 32 + m;
  bf16x8 qf[4];
#pragma unroll
  for (int ks = 0; ks < 4; ++ks) {
    const int pos = (ks * 2 + hi + qrow) & 7;
    qf[ks] = *(const bf16x8*)(Qh + (size_t)qrow * 64 + pos * 8);
  }

  bf16x8 onesB;
#pragma unroll
  for (int i = 0; i < 8; ++i) onesB[i] = (short)0x3F80;   // bf16 1.0

  f32x16 o0, o1, sl;
#pragma unroll
  for (int i = 0; i < 16; ++i) { o0[i] = 0.f; o1[i] = 0.f; sl[i] = 0.f; }

  // ---- hoisted per-lane stage offsets ----
  const int i0 = w * 2, i1 = w * 2 + 1;
  const size_t kOff0 = (size_t)i0 * 512 + l * 8;
  const size_t kOff1 = (size_t)i1 * 512 + l * 8;
  const int dd0 = i0 * 8 + (l >> 3), dd1 = i1 * 8 + (l >> 3);
  const int p_ = l & 7;
  const int q0 = (p_ - dd0) & 7, q1 = (p_ - dd1) & 7;
  const size_t vE0 = (size_t)dd0 * 2048 + (size_t)(((q0 + dd0) & 15)) * 8;
  const size_t vO0 = (size_t)dd0 * 2048 + (size_t)(((8 + q0 + dd0) & 15)) * 8;
  const size_t vE1 = (size_t)dd1 * 2048 + (size_t)(((q1 + dd1) & 15)) * 8;
  const size_t vO1 = (size_t)dd1 * 2048 + (size_t)(((8 + q1 + dd1) & 15)) * 8;

  // stage 64-key block kb (absolute, 0..31) into buf
  auto stage = [&](int kb, int buf) {
    const u16* kp = Kh + (size_t)kb * 4096;
    gld16(kp + kOff0, &Ks[z][buf][i0 * 512]);
    gld16(kp + kOff1, &Ks[z][buf][i1 * 512]);
    const u16* vp = Vh + (size_t)(kb >> 1) * 128;
    const int odd = kb & 1;
    gld16(vp + (odd ? vO0 : vE0), &Vs[z][buf][i0 * 512]);
    gld16(vp + (odd ? vO1 : vE1), &Vs[z][buf][i1 * 512]);
  };

  int cur = 0;
  stage(z * 16, 0);

  for (int kt = 0; kt < 16; ++kt) {
    __builtin_amdgcn_s_barrier();      // buf[cur^1] readers (kt-1) done
    if (kt < 15) {
      stage(z * 16 + kt + 1, cur ^ 1);
      asm volatile("s_waitcnt vmcnt(4)" ::: "memory");  // kt's 4 landed
    } else {
      asm volatile("s_waitcnt vmcnt(0)" ::: "memory");
    }
    __builtin_amdgcn_s_barrier();      // buf[cur] visible block-wide

#pragma unroll
    for (int g = 0; g < 2; ++g) {
      f32x16 st;
#pragma unroll
      for (int i = 0; i < 16; ++i) st[i] = 0.f;
      const int key = g * 32 + m;
      __builtin_amdgcn_s_setprio(1);
#pragma unroll
      for (int ks = 0; ks < 4; ++ks) {
        const int pos = (ks * 2 + hi + key) & 7;
        bf16x8 kf = *(const bf16x8*)(&Ks[z][cur][key * 64 + pos * 8]);
        st = __builtin_amdgcn_mfma_f32_32x32x16_bf16(kf, qf[ks], st, 0, 0, 0);
      }
      __builtin_amdgcn_s_setprio(0);

      float p[16];
#pragma unroll
      for (int r = 0; r < 16; ++r) p[r] = fast_exp2(st[r]);

      unsigned W[8];
#pragma unroll
      for (int i = 0; i < 8; ++i) W[i] = cvtpk(p[2 * i], p[2 * i + 1]);

#pragma unroll
      for (int s = 0; s < 2; ++s) {
        unsigned w0 = W[4 * s], w1 = W[4 * s + 1];
        unsigned w2 = W[4 * s + 2], w3 = W[4 * s + 3];
        asm("v_permlane32_swap_b32 %0, %1" : "+v"(w0), "+v"(w2));
        asm("v_permlane32_swap_b32 %0, %1" : "+v"(w1), "+v"(w3));
        int4 fd;
        fd.x = (int)w0;
        fd.y = (int)w1;
        fd.z = (int)w2;
        fd.w = (int)w3;
        union { int4 i; bf16x8 v; } pu; pu.i = fd;
        const int c = g * 4 + s * 2 + hi;   // local key chunk 0..7
        __builtin_amdgcn_s_setprio(1);
        sl = __builtin_amdgcn_mfma_f32_32x32x16_bf16(pu.v, onesB, sl, 0, 0, 0);
#pragma unroll
        for (int n = 0; n < 2; ++n) {
          const int d = n * 32 + m;
          const int pos = (c + d) & 7;
          bf16x8 vf = *(const bf16x8*)(&Vs[z][cur][d * 64 + pos * 8]);
          if (n == 0) o0 = __builtin_amdgcn_mfma_f32_32x32x16_bf16(pu.v, vf, o0, 0, 0, 0);
          else        o1 = __builtin_amdgcn_mfma_f32_32x32x16_bf16(pu.v, vf, o1, 0, 0, 0);
        }
        __builtin_amdgcn_s_setprio(0);
      }
    }
    cur ^= 1;
  }
  __syncthreads();   // all compute done before Ks/Vs are reused below

  // ---- in-block z combine (Ks/Vs are dead after the post-loop barrier) ----
  float* Osl = (float*)Ks;   // 4 waves x 32 rows x 64 dims f32 = 32 KiB (exact)
  float* Lz1 = (float*)Vs;   // 4 waves x 32 rowsums

  if (z == 1) {
    if (m == 0) {
#pragma unroll
      for (int r = 0; r < 16; ++r) {
        const int qlocal = (r & 3) + 8 * (r >> 2) + 4 * hi;
        Lz1[w * 32 + qlocal] = sl[r];   // all cols identical; col m=0 lane writes
      }
    }
#pragma unroll
    for (int r = 0; r < 16; ++r) {
      const int qlocal = (r & 3) + 8 * (r >> 2) + 4 * hi;
      Osl[w * 2048 + qlocal * 64 + m] = o0[r];
      Osl[w * 2048 + qlocal * 64 + 32 + m] = o1[r];
    }
  }
  __syncthreads();
  if (z == 0) {
    const int b = head >> 4, h = head & 15;
#pragma unroll
    for (int r = 0; r < 16; ++r) {
      const int qlocal = (r & 3) + 8 * (r >> 2) + 4 * hi;
      const float lfull = sl[r] + Lz1[w * 32 + qlocal];
      const float inv = 1.0f / lfull;
      const float v0 = (o0[r] + Osl[w * 2048 + qlocal * 64 + m]) * inv;
      const float v1 = (o1[r] + Osl[w * 2048 + qlocal * 64 + 32 + m]) * inv;
      const size_t base =
          ((size_t)(b * 2048 + qt * 128 + w * 32 + qlocal)) * 1024 + h * 64;
      Ob[base + m] = f2bf(v0);
      Ob[base + 32 + m] = f2bf(v1);
    }
  }
}

// ---------- proj GEMM: 128x64 tiles, 512 blocks (2/CU), plain stores ----------
__global__ __launch_bounds__(256) void proj_gemm_kernel(
    const u16* __restrict__ A, const u16* __restrict__ Bt,
    const float* __restrict__ bias, float* __restrict__ out) {
  __shared__ u16 sm[6144];   // As 128x32 (4096) + Bs 64x32 (2048)
  u16* As = sm;
  u16* Bs = sm + 4096;
  const int tid = threadIdx.x;
  const int w = tid >> 6, l = tid & 63, quad = l >> 4, lanelo = l & 15;
  const int wr = w >> 1, wc = w & 1;
  const int flat = blockIdx.x + 32 * blockIdx.y;       // 0..511
  const int xcd = flat & 7, lid = flat >> 3;
  const long m0 = (long)(xcd * 4 + (lid & 3)) * 128;
  const long n0 = (long)(lid >> 2) * 64;

  f32x4 acc[4][2];
#pragma unroll
  for (int i = 0; i < 4; ++i)
#pragma unroll
    for (int j = 0; j < 2; ++j) acc[i][j] = (f32x4){0.f, 0.f, 0.f, 0.f};

  const u16* ag = A + (m0 + w * 32 + (l >> 2)) * 1024 + (l & 3) * 8;
  const u16* bg = Bt + (n0 + w * 16 + (l >> 2)) * 1024 + (l & 3) * 8;
  u16* asl = As + w * 1024;
  u16* bsl = Bs + w * 512;

  for (int kt = 0; kt < 32; ++kt) {
    const int ko = kt * 32;
    gld16(ag + ko, asl);
    gld16(ag + 16 * 1024 + ko, asl + 512);
    gld16(bg + ko, bsl);
    __syncthreads();
    bf16x8 af[4], bf[2];
#pragma unroll
    for (int mt = 0; mt < 4; ++mt)
      af[mt] = *(const bf16x8*)(As + (wr * 64 + mt * 16 + lanelo) * 32 + quad * 8);
#pragma unroll
    for (int nt = 0; nt < 2; ++nt)
      bf[nt] = *(const bf16x8*)(Bs + (wc * 32 + nt * 16 + lanelo) * 32 + quad * 8);
#pragma unroll
    for (int mt = 0; mt < 4; ++mt)
#pragma unroll
      for (int nt = 0; nt < 2; ++nt)
        acc[mt][nt] = __builtin_amdgcn_mfma_f32_16x16x32_bf16(af[mt], bf[nt], acc[mt][nt], 0, 0, 0);
    __syncthreads();
  }

  float bias_v[2];
#pragma unroll
  for (int nt = 0; nt < 2; ++nt)
    bias_v[nt] = bias[n0 + wc * 32 + nt * 16 + lanelo];

#pragma unroll
  for (int mt = 0; mt < 4; ++mt)
#pragma unroll
    for (int nt = 0; nt < 2; ++nt)
#pragma unroll
      for (int r = 0; r < 4; ++r) {
        const size_t mm = m0 + wr * 64 + mt * 16 + quad * 4 + r;
        const size_t nn = n0 + wc * 32 + nt * 16 + lanelo;
        out[mm * 1024 + nn] = acc[mt][nt][r] + bias_v[nt];
      }
}

// ---------- launch ----------
extern "C" void kernel_launch(void* const* d_in, const int* in_sizes, int n_in,
                              void* d_out, int out_size, void* d_ws, size_t ws_size,
                              hipStream_t stream) {
  const float* x = (const float*)d_in[0];
  const float* Wqkv = (const float*)d_in[1];
  const float* bqkv = (const float*)d_in[2];
  const float* Wproj = (const float*)d_in[3];
  const float* bproj = (const float*)d_in[4];
  float* out = (float*)d_out;
  char* ws = (char*)d_ws;

  // workspace layout (42 MB), lifetime-based aliasing:
  //  [ 0..8M)   Xb (dead after qkv) -> Ob (attn out / proj in)
  //  [ 8..16M)  Wqkt ; [16..24M) Qb ; [24..32M) Kb ; [32..40M) Vtb ; [40..42M) Wpt
  u16* Xb   = (u16*)(ws);
  u16* Ob   = (u16*)(ws);
  u16* Wqkt = (u16*)(ws + 8388608);
  u16* Qb   = (u16*)(ws + 16777216);
  u16* Kb   = (u16*)(ws + 25165824);
  u16* Vtb  = (u16*)(ws + 33554432);
  u16* Wpt  = (u16*)(ws + 41943040);

  prep_kernel<<<6144, 256, 0, stream>>>(x, Xb, Wqkv, Wqkt, Wproj, Wpt);
  qkv_gemm_kernel<<<dim3(32, 24), 256, 0, stream>>>(Xb, Wqkt, bqkv, Qb, Kb, Vtb);
  attn_kernel<<<512, 512, 0, stream>>>(Qb, Kb, Vtb, Ob);
  proj_gemm_kernel<<<dim3(32, 16), 256, 0, stream>>>(Ob, Wpt, bproj, out);
}